// Round 14
// baseline (189.412 us; speedup 1.0000x reference)
//
#include <hip/hip_runtime.h>

#define HW    96
#define NPIX  9216        // 96*96
#define NCH   64          // C
#define INNER 3
#define NDIL  3
#define BB    2           // batch
#define TOTPIX (BB * NPIX)   // 18432
#define NT32  (NPIX / 32)    // 288 key tiles per batch

typedef __attribute__((ext_vector_type(8))) short short8;            // 8 bf16
typedef __attribute__((ext_vector_type(8))) unsigned short ushort8;  // 8 bf16 raw
typedef __attribute__((ext_vector_type(4))) float f32x4;
typedef __attribute__((ext_vector_type(4))) unsigned int uint32x4;

__device__ __forceinline__ ushort f2bf_rne(float f) {
    unsigned u = __float_as_uint(f);
    u += 0x7fffu + ((u >> 16) & 1u);
    return (ushort)(u >> 16);
}
__device__ __forceinline__ float bf2f(ushort u) {
    return __uint_as_float((unsigned)u << 16);
}
// pack hi16(a),hi16(b) -> dword {bf16(b)<<16 | bf16(a)} (trunc; ratio-safe for P)
__device__ __forceinline__ unsigned pack_bf(float lo, float hi) {
    return __builtin_amdgcn_perm(__float_as_uint(hi), __float_as_uint(lo), 0x07060302u);
}

// ---------------------------------------------------------------------------
// Kernel 1: x_red = 1x1 conv (64 -> 3 channels). 4-way channel split +
// LDS reduce (R7). Also zeroes L.
// ---------------------------------------------------------------------------
__global__ __launch_bounds__(256) void
k_reduce(const float* __restrict__ x, const float* __restrict__ w_red,
         const float* __restrict__ b_red, float* __restrict__ xred,
         float* __restrict__ L) {
    __shared__ float part[4][3][64];
    int tid = threadIdx.x;
    int gid = blockIdx.x * 256 + tid;
    if (gid < TOTPIX) L[gid] = 0.f;            // fold memset into this kernel
    int cp = tid >> 6, lane = tid & 63;
    int pix = blockIdx.x * 64 + lane;           // block never straddles b
    int b = pix / NPIX, n = pix % NPIX;
    const float* xb = x + (size_t)b * NCH * NPIX + (size_t)(cp * 16) * NPIX + n;
    float a0 = 0.f, a1 = 0.f, a2 = 0.f;
    #pragma unroll
    for (int c = 0; c < 16; ++c) {
        float xv = xb[(size_t)c * NPIX];
        a0 = fmaf(w_red[0 * NCH + cp * 16 + c], xv, a0);
        a1 = fmaf(w_red[1 * NCH + cp * 16 + c], xv, a1);
        a2 = fmaf(w_red[2 * NCH + cp * 16 + c], xv, a2);
    }
    part[cp][0][lane] = a0; part[cp][1][lane] = a1; part[cp][2][lane] = a2;
    __syncthreads();
    if (tid < 192) {
        int o = tid >> 6, lp = tid & 63;
        float s = ((part[0][o][lp] + part[1][o][lp]) +
                   (part[2][o][lp] + part[3][o][lp])) + b_red[o];
        int pix2 = blockIdx.x * 64 + lp;
        int b2 = pix2 / NPIX, n2 = pix2 % NPIX;
        xred[((size_t)b2 * INNER + o) * NPIX + n2] = s;
    }
}

// ---------------------------------------------------------------------------
// Kernel 2a: features. thread = (pixel, dilation i3, out-channel o) (R7).
// Writes FT[j][pix] bf16, j = i3*18 + t*3 + o. Rows 54..63 never written —
// zero-weighted in k_fuse.
// ---------------------------------------------------------------------------
__global__ __launch_bounds__(256) void
k_feat(const float* __restrict__ xred, const float* __restrict__ w_dil,
       const float* __restrict__ b_dil, ushort* __restrict__ FT) {
    int gid = blockIdx.x * 256 + threadIdx.x;      // 9 * 18432 threads exactly
    int io = gid / TOTPIX;                          // wave-uniform (TOTPIX%64==0)
    int pix = gid - io * TOTPIX;
    int i3 = io / 3, o = io - 3 * i3;
    int b = pix / NPIX, n = pix % NPIX;
    int h = n / HW, w = n % HW;
    const float* xr = xred + (size_t)b * INNER * NPIX;
    int d = i3 + 1;

    float co = b_dil[i3 * 3 + o];
    #pragma unroll
    for (int ci = 0; ci < 3; ++ci) {
        const float* xo = xr + ci * NPIX;
        #pragma unroll
        for (int kh = 0; kh < 3; ++kh) {
            int hh = h + (kh - 1) * d;
            #pragma unroll
            for (int kw = 0; kw < 3; ++kw) {
                int ww = w + (kw - 1) * d;
                float v = ((unsigned)hh < HW && (unsigned)ww < HW) ? xo[hh * HW + ww] : 0.f;
                co = fmaf(w_dil[(9 * i3 + 3 * o + ci) * 9 + kh * 3 + kw], v, co);
            }
        }
    }

    const float* xo = xr + o * NPIX;
    float tf0 = xo[h * HW + w];
    float tf1 = xo[h * HW + (HW - 1 - w)];
    float tf2 = xo[(HW - 1 - h) * HW + w];
    float tf3 = xo[w * HW + (HW - 1 - h)];
    float tf4 = xo[(HW - 1 - h) * HW + (HW - 1 - w)];
    float tf5 = xo[(HW - 1 - w) * HW + h];

    size_t base = (size_t)(i3 * 18 + o) * TOTPIX + pix;
    FT[base + (size_t)(0 * 3) * TOTPIX] = f2bf_rne(co * tf0);
    FT[base + (size_t)(1 * 3) * TOTPIX] = f2bf_rne(co * tf1);
    FT[base + (size_t)(2 * 3) * TOTPIX] = f2bf_rne(co * tf2);
    FT[base + (size_t)(3 * 3) * TOTPIX] = f2bf_rne(co * tf3);
    FT[base + (size_t)(4 * 3) * TOTPIX] = f2bf_rne(co * tf4);
    FT[base + (size_t)(5 * 3) * TOTPIX] = f2bf_rne(co * tf5);
}

// ---------------------------------------------------------------------------
// Kernel 2b: fuse conv as MFMA GEMM, 64 px/block (grid 288).
// tokTt is TILED (unpermuted): [b][n>>5][c][n&31]. The in-register-P key
// permutation is applied in k_attn's ldsV staging offsets.
// ---------------------------------------------------------------------------
__global__ __launch_bounds__(256) void
k_fuse(const ushort* __restrict__ FT, const float* __restrict__ w_fuse,
       const float* __restrict__ b_fuse, ushort* __restrict__ tok,
       ushort* __restrict__ tokTt) {
    __shared__ ushort wpad[64 * 72];     // [c][j pad 72]
    __shared__ float  bsh[64];
    __shared__ ushort tile[64 * 72];     // [c][64 px + 8 pad]

    int tid = threadIdx.x;
    for (int i = tid; i < 64 * 64; i += 256) {
        int c = i >> 6, j = i & 63;
        wpad[c * 72 + j] = (j < 54) ? f2bf_rne(w_fuse[c * 54 + j]) : (ushort)0;
    }
    if (tid < 64) bsh[tid] = b_fuse[tid];
    __syncthreads();

    int wv = tid >> 6, lane = tid & 63, quad = lane >> 4, l15 = lane & 15;
    int px0 = blockIdx.x * 64;

    short8 af[4][2];
    #pragma unroll
    for (int m = 0; m < 4; ++m)
        #pragma unroll
        for (int kc = 0; kc < 2; ++kc)
            af[m][kc] = *(const short8*)&wpad[(16 * m + l15) * 72 + quad * 8 + 32 * kc];

    f32x4 acc[4];
    #pragma unroll
    for (int m = 0; m < 4; ++m) acc[m] = (f32x4){0.f, 0.f, 0.f, 0.f};

    int px = px0 + wv * 16 + l15;
    #pragma unroll
    for (int kc = 0; kc < 2; ++kc) {
        short8 bf;
        #pragma unroll
        for (int jj = 0; jj < 8; ++jj)
            bf[jj] = (short)FT[(size_t)(quad * 8 + jj + 32 * kc) * TOTPIX + px];
        #pragma unroll
        for (int m = 0; m < 4; ++m)
            acc[m] = __builtin_amdgcn_mfma_f32_16x16x32_bf16(af[m][kc], bf, acc[m], 0, 0, 0);
    }

    #pragma unroll
    for (int m = 0; m < 4; ++m)
        #pragma unroll
        for (int r = 0; r < 4; ++r) {
            int c = 16 * m + quad * 4 + r;
            tile[c * 72 + wv * 16 + l15] = f2bf_rne(acc[m][r] + bsh[c]);
        }
    __syncthreads();

    int b0 = px0 / NPIX, n0 = px0 % NPIX;
    {   // tok[b][n][c]
        int lp = tid >> 2, part = tid & 3;
        ushort row[16];
        #pragma unroll
        for (int k = 0; k < 16; ++k) row[k] = tile[(part * 16 + k) * 72 + lp];
        ushort* dst = tok + ((size_t)b0 * NPIX + n0 + lp) * NCH + part * 16;
        *(ushort8*)&dst[0] = *(const ushort8*)&row[0];
        *(ushort8*)&dst[8] = *(const ushort8*)&row[8];
    }
    {   // tokTt[b][n>>5][c][n&31] (32-key tiles)
        int c = tid >> 2, seg = tid & 3;
        int n = n0 + seg * 16;
        size_t base = (((size_t)b0 * NT32 + (n >> 5)) * 64 + c) * 32 + (n & 31);
        *(ushort8*)&tokTt[base]     = *(const ushort8*)&tile[c * 72 + seg * 16];
        *(ushort8*)&tokTt[base + 8] = *(const ushort8*)&tile[c * 72 + seg * 16 + 8];
    }
}

// ---------------------------------------------------------------------------
// Kernel 3: MFMA flash attention — R13 structure (full-line epilogue, XCD
// swizzle, -FM in MFMA C-seed, ones-MFMA denominator, P=8) with ONE change:
// __launch_bounds__(256,5). R13's counters showed occupancy 26.6% = the
// (256,4) 128-reg budget caps residency at 4 blocks/CU, so grid 1152
// (= 4.5 blocks/CU) split into a 4-block generation + a 0.5-block straggler
// generation (~2x wall). Actual use is 96 regs (56 arch + 40 acc) <= 102,
// so the 5-wave bracket fits without spill (R8 precedent: 96 total at
// (256,5), no spill) -> capacity 1280 >= 1152 = single generation, no tail.
// ---------------------------------------------------------------------------
__global__ __launch_bounds__(256, 5) void
k_attn(const ushort* __restrict__ tok, const ushort* __restrict__ tokTt,
       float* __restrict__ L, ushort* __restrict__ pacc, int P, int KP) {
    // staging: ldsK 2x[32*72]=4608 | ldsV 2x[64*40]=5120  (9728 ushorts, 19456 B)
    // epilogue reuse: ot [64][136] = 8704 ushorts
    __shared__ ushort smem[9728];
    ushort* ldsK = smem;            // [cur][key][64ch + 8 pad], cur stride 2304
    ushort* ldsV = smem + 4608;     // [cur][ch][32pos + 8 pad], cur stride 2560

    const int QW = NPIX / 128;          // 72 query chunks per batch
    int bid0 = blockIdx.x;
    int nwg = gridDim.x;                // divisible by 8 for all P candidates
    int bid = (bid0 & 7) * (nwg >> 3) + (bid0 >> 3);   // XCD-chunked swizzle
    int qc = bid % QW; int rest = bid / QW;
    int p = rest % P;  int b = rest / P;
    int tid = threadIdx.x;
    int wv = tid >> 6, lane = tid & 63;
    int quad = lane >> 4, l15 = lane & 15;

    const ushort* tb  = tok + (size_t)b * NPIX * NCH;
    const ushort* tvb = tokTt + (size_t)b * NT32 * (64 * 32);
    int qwave = qc * 128 + wv * 32;

    // staging decomposition (per thread: one 16B chunk of each tile)
    int sk_off = (tid >> 3) * 72 + (tid & 7) * 8;   // [key=tid>>3][ch=(tid&7)*8]
    // V: thread stages ch=tid>>2, keys kk=(tid&3)*8+e. Permuted destination:
    // e=0..3 -> pos base0+e, e=4..7 -> pos base1+(e&3)  (bijective; pairs with
    // the in-register-P key ordering pos = 8*quad + 4*m2 + reg)
    int svj = tid & 3;
    int sv_b0 = (tid >> 2) * 40 + 8 * ((2 * svj) & 3) + 4 * (svj >> 1);
    int sv_b1 = (tid >> 2) * 40 + 8 * ((2 * svj + 1) & 3) + 4 * (svj >> 1);

    // Q fragments: B operand of S^T (lane q=16n+l15, k=quad*8+j+32kc); scale folded.
    short8 qf[2][2];
    const float scale = 0.125f * 1.44269504088896340736f;  // 1/sqrt(C) * log2(e)
    #pragma unroll
    for (int n = 0; n < 2; ++n) {
        const ushort* qr = tb + (size_t)(qwave + 16 * n + l15) * NCH + quad * 8;
        #pragma unroll
        for (int kc = 0; kc < 2; ++kc) {
            ushort8 raw = *(const ushort8*)(qr + 32 * kc);
            short8 f;
            #pragma unroll
            for (int e = 0; e < 8; ++e) f[e] = (short)f2bf_rne(bf2f(raw[e]) * scale);
            qf[n][kc] = f;
        }
    }

    f32x4 O[4][2];                      // O^T acc: D[c=16m+quad*4+reg][q=16n+l15]
    #pragma unroll
    for (int m = 0; m < 4; ++m)
        #pragma unroll
        for (int n = 0; n < 2; ++n) O[m][n] = (f32x4){0.f, 0.f, 0.f, 0.f};
    f32x4 Lacc[2];                      // denominator acc (ones-MFMA), reg 0 used
    Lacc[0] = (f32x4){0.f, 0.f, 0.f, 0.f};
    Lacc[1] = (f32x4){0.f, 0.f, 0.f, 0.f};

    const float FM = 16.0f;             // fixed exp2-domain shift
    const f32x4 FMc = (f32x4){-FM, -FM, -FM, -FM};   // folded into S C-seed
    short8 ones8;
    #pragma unroll
    for (int e = 0; e < 8; ++e) ones8[e] = (short)0x3F80;   // bf16 1.0

    int k0 = p * KP;
    int nt = KP / 32;

    // strength-reduced staging pointers (advance one 32-key tile per body)
    const ushort* pK = tb + (size_t)k0 * NCH + tid * 8;
    const ushort* pV = tvb + ((size_t)(k0 >> 5)) * 2048 + tid * 8;

    // prologue: stage tile 0
    {
        ushort8 gK = *(const ushort8*)pK;
        ushort8 gV = *(const ushort8*)pV;
        *(ushort8*)&ldsK[sk_off] = gK;
        uint32x4 v4 = *(uint32x4*)&gV;
        *(uint2*)&ldsV[sv_b0] = make_uint2(v4.x, v4.y);
        *(uint2*)&ldsV[sv_b1] = make_uint2(v4.z, v4.w);
    }
    __syncthreads();

    for (int t = 0; t < nt; ++t) {
        int curK = (t & 1) * 2304, curV = (t & 1) * 2560;
        bool pre = (t + 1 < nt);
        pK += 32 * NCH;  pV += 2048;

        // issue next tile's global loads EARLY (latency hides under S phase)
        ushort8 nK, nV;
        if (pre) {
            nK = *(const ushort8*)pK;
            nV = *(const ushort8*)pV;
        }

        // K fragments from LDS (shared by all 4 waves)
        short8 kd[4];
        #pragma unroll
        for (int m2 = 0; m2 < 2; ++m2)
            #pragma unroll
            for (int kc = 0; kc < 2; ++kc)
                kd[2 * m2 + kc] = *(const short8*)&ldsK[curK + (16 * m2 + l15) * 72 +
                                                       quad * 8 + 32 * kc];

        // S^T per-m2 half: 4 MFMA (C seeded with -FM) -> 8 exp2 -> pack
        uint32x4 wac[2];
        #pragma unroll
        for (int m2 = 0; m2 < 2; ++m2) {
            f32x4 Sm[2];
            __builtin_amdgcn_s_setprio(1);
            #pragma unroll
            for (int n = 0; n < 2; ++n) {
                Sm[n] = __builtin_amdgcn_mfma_f32_16x16x32_bf16(kd[2 * m2 + 0],
                                                                qf[n][0], FMc, 0, 0, 0);
                Sm[n] = __builtin_amdgcn_mfma_f32_16x16x32_bf16(kd[2 * m2 + 1],
                                                                qf[n][1], Sm[n], 0, 0, 0);
            }
            __builtin_amdgcn_s_setprio(0);
            #pragma unroll
            for (int n = 0; n < 2; ++n) {
                float e0 = __builtin_amdgcn_exp2f(Sm[n][0]);
                float e1 = __builtin_amdgcn_exp2f(Sm[n][1]);
                float e2 = __builtin_amdgcn_exp2f(Sm[n][2]);
                float e3 = __builtin_amdgcn_exp2f(Sm[n][3]);
                if (m2 == 0) {
                    wac[n].x = pack_bf(e0, e1); wac[n].y = pack_bf(e2, e3);
                } else {
                    wac[n].z = pack_bf(e0, e1); wac[n].w = pack_bf(e2, e3);
                }
            }
        }

        // retire staging regs into the OTHER buffer (safe: all reads of that
        // buffer completed before the last barrier)
        if (pre) {
            *(ushort8*)&ldsK[(curK ^ 2304) + sk_off] = nK;
            uint32x4 v4 = *(uint32x4*)&nV;
            *(uint2*)&ldsV[(curV ^ 2560) + sv_b0] = make_uint2(v4.x, v4.y);
            *(uint2*)&ldsV[(curV ^ 2560) + sv_b1] = make_uint2(v4.z, v4.w);
        }

        // V^T fragments (A[ch][pos]) from LDS (permuted key-positions)
        short8 vf[4];
        #pragma unroll
        for (int mc = 0; mc < 4; ++mc)
            vf[mc] = *(const short8*)&ldsV[curV + (16 * mc + l15) * 40 + quad * 8];

        // O^T += V^T·P^T and L += 1^T·P^T (K=32): all operands in registers
        __builtin_amdgcn_s_setprio(1);
        #pragma unroll
        for (int n = 0; n < 2; ++n) {
            short8 bfr = *(short8*)&wac[n];
            #pragma unroll
            for (int mc = 0; mc < 4; ++mc)
                O[mc][n] = __builtin_amdgcn_mfma_f32_16x16x32_bf16(vf[mc], bfr,
                                                                   O[mc][n], 0, 0, 0);
            Lacc[n] = __builtin_amdgcn_mfma_f32_16x16x32_bf16(ones8, bfr,
                                                              Lacc[n], 0, 0, 0);
        }
        __builtin_amdgcn_s_setprio(0);

        __syncthreads();               // also guards smem reuse by the epilogue
    }

    if (quad == 0) {                    // Lacc[n][0] = full 32-key-tile sums
        #pragma unroll
        for (int n = 0; n < 2; ++n)
            atomicAdd(&L[(size_t)b * NPIX + qwave + 16 * n + l15], Lacc[n][0]);
    }

    // ---- epilogue: O -> smem tile [64][136], then FULL-LINE pacc writeout ----
    #pragma unroll
    for (int n = 0; n < 2; ++n) {
        int ql = wv * 32 + 16 * n + l15;
        #pragma unroll
        for (int m = 0; m < 4; ++m)
            #pragma unroll
            for (int r = 0; r < 4; ++r)
                smem[(16 * m + quad * 4 + r) * 136 + ql] = f2bf_rne(O[m][n][r]);
    }
    __syncthreads();
    size_t bp = (size_t)b * P + p;
    #pragma unroll
    for (int i = 0; i < 4; ++i) {
        int lin = i * 2048 + tid * 8;
        int c = lin >> 7, q = lin & 127;
        // 16 consecutive lanes cover one 256B row = 4 full 64B lines
        *(ushort8*)(pacc + (bp * NCH + c) * NPIX + qc * 128 + q) =
            *(const ushort8*)&smem[c * 136 + q];
    }
}

// ---------------------------------------------------------------------------
// Kernel 4: fully-coalesced combine with inline normalization. thread =
// (b, c, 8-n segment): o[n] = sum_p pacc[b][p][c][n], out = x + 0.2/L * o.
// ---------------------------------------------------------------------------
__global__ void k_combine(const float* __restrict__ x, const float* __restrict__ L,
                          const ushort* __restrict__ pacc, float* __restrict__ out,
                          int P) {
    int gid = blockIdx.x * blockDim.x + threadIdx.x;   // (b*NCH + c)*1152 + seg
    if (gid >= BB * NCH * (NPIX / 8)) return;
    int seg = gid % (NPIX / 8);
    int bc  = gid / (NPIX / 8);
    int b = bc / NCH;
    int n0 = seg * 8;
    float o[8] = {0.f, 0.f, 0.f, 0.f, 0.f, 0.f, 0.f, 0.f};
    for (int p = 0; p < P; ++p) {
        ushort8 t = *(const ushort8*)(pacc +
            (((size_t)b * P + p) * NCH + (bc % NCH)) * NPIX + n0);
        #pragma unroll
        for (int e = 0; e < 8; ++e) o[e] += bf2f(t[e]);
    }
    const float* lv = L + (size_t)b * NPIX + n0;
    const float* xb = x + (size_t)bc * NPIX + n0;
    float* ob = out + (size_t)bc * NPIX + n0;
    #pragma unroll
    for (int e = 0; e < 8; ++e)
        ob[e] = fmaf(0.2f / lv[e], o[e], xb[e]);
}

// ---------------------------------------------------------------------------
extern "C" void kernel_launch(void* const* d_in, const int* in_sizes, int n_in,
                              void* d_out, int out_size, void* d_ws, size_t ws_size,
                              hipStream_t stream) {
    const float* x      = (const float*)d_in[0];
    const float* w_red  = (const float*)d_in[1];
    const float* b_red  = (const float*)d_in[2];
    const float* w_dil  = (const float*)d_in[3];
    const float* b_dil  = (const float*)d_in[4];
    const float* w_fuse = (const float*)d_in[5];
    const float* b_fuse = (const float*)d_in[6];
    float* out = (float*)d_out;

    // ws: xred f32 | FT bf16 | tok bf16 | tokTt bf16 | L f32 | pacc bf16
    const size_t XRED_N = (size_t)BB * INNER * NPIX;
    const size_t FT_N   = (size_t)64 * TOTPIX;
    const size_t TOK_N  = (size_t)BB * NPIX * NCH;
    const size_t HEAD_B = XRED_N * 4 + (FT_N + 2 * TOK_N) * 2 + TOTPIX * 4;
    int P = 0;
    // P=8: grid 1152 <= 1280 residency slots at 5 blocks/CU -> single
    // generation; pacc traffic half of P=16. KP = NPIX/P multiple of 32 for
    // all cands; grid divisible by 8 (XCD swizzle).
    const int cands[4] = {8, 4, 2, 1};
    for (int ci = 0; ci < 4; ++ci) {
        int cp = cands[ci];
        size_t need = HEAD_B + (size_t)BB * cp * NPIX * NCH * 2;
        if (ws_size >= need) { P = cp; break; }
    }
    if (P == 0) return;

    float*  xred  = (float*)d_ws;
    ushort* FT    = (ushort*)(xred + XRED_N);
    ushort* tok   = FT + FT_N;
    ushort* tokTt = tok + TOK_N;
    float*  L     = (float*)(tokTt + TOK_N);
    ushort* pacc  = (ushort*)(L + TOTPIX);

    k_reduce <<<TOTPIX / 64, 256, 0, stream>>>(x, w_red, b_red, xred, L);
    k_feat   <<<9 * TOTPIX / 256, 256, 0, stream>>>(xred, w_dil, b_dil, FT);
    k_fuse   <<<TOTPIX / 64, 256, 0, stream>>>(FT, w_fuse, b_fuse, tok, tokTt);
    k_attn   <<<BB * P * (NPIX / 128), 256, 0, stream>>>(tok, tokTt, L, pacc,
                                                         P, NPIX / P);
    k_combine<<<(BB * NCH * (NPIX / 8) + 255) / 256, 256, 0, stream>>>(x, L, pacc,
                                                                       out, P);
}

// Round 15
// 137.222 us; speedup vs baseline: 1.3803x; 1.3803x over previous
//
#include <hip/hip_runtime.h>

#define HW    96
#define NPIX  9216        // 96*96
#define NCH   64          // C
#define INNER 3
#define NDIL  3
#define BB    2           // batch
#define TOTPIX (BB * NPIX)   // 18432
#define NT32  (NPIX / 32)    // 288 key tiles per batch

typedef __attribute__((ext_vector_type(8))) short short8;            // 8 bf16
typedef __attribute__((ext_vector_type(8))) unsigned short ushort8;  // 8 bf16 raw
typedef __attribute__((ext_vector_type(4))) float f32x4;
typedef __attribute__((ext_vector_type(4))) unsigned int uint32x4;

__device__ __forceinline__ ushort f2bf_rne(float f) {
    unsigned u = __float_as_uint(f);
    u += 0x7fffu + ((u >> 16) & 1u);
    return (ushort)(u >> 16);
}
__device__ __forceinline__ float bf2f(ushort u) {
    return __uint_as_float((unsigned)u << 16);
}
// pack hi16(a),hi16(b) -> dword {bf16(b)<<16 | bf16(a)} (trunc; ratio-safe for P)
__device__ __forceinline__ unsigned pack_bf(float lo, float hi) {
    return __builtin_amdgcn_perm(__float_as_uint(hi), __float_as_uint(lo), 0x07060302u);
}

// ---------------------------------------------------------------------------
// Kernel 1: x_red = 1x1 conv (64 -> 3 channels). 4-way channel split +
// LDS reduce (R7). Also zeroes L.
// ---------------------------------------------------------------------------
__global__ __launch_bounds__(256) void
k_reduce(const float* __restrict__ x, const float* __restrict__ w_red,
         const float* __restrict__ b_red, float* __restrict__ xred,
         float* __restrict__ L) {
    __shared__ float part[4][3][64];
    int tid = threadIdx.x;
    int gid = blockIdx.x * 256 + tid;
    if (gid < TOTPIX) L[gid] = 0.f;            // fold memset into this kernel
    int cp = tid >> 6, lane = tid & 63;
    int pix = blockIdx.x * 64 + lane;           // block never straddles b
    int b = pix / NPIX, n = pix % NPIX;
    const float* xb = x + (size_t)b * NCH * NPIX + (size_t)(cp * 16) * NPIX + n;
    float a0 = 0.f, a1 = 0.f, a2 = 0.f;
    #pragma unroll
    for (int c = 0; c < 16; ++c) {
        float xv = xb[(size_t)c * NPIX];
        a0 = fmaf(w_red[0 * NCH + cp * 16 + c], xv, a0);
        a1 = fmaf(w_red[1 * NCH + cp * 16 + c], xv, a1);
        a2 = fmaf(w_red[2 * NCH + cp * 16 + c], xv, a2);
    }
    part[cp][0][lane] = a0; part[cp][1][lane] = a1; part[cp][2][lane] = a2;
    __syncthreads();
    if (tid < 192) {
        int o = tid >> 6, lp = tid & 63;
        float s = ((part[0][o][lp] + part[1][o][lp]) +
                   (part[2][o][lp] + part[3][o][lp])) + b_red[o];
        int pix2 = blockIdx.x * 64 + lp;
        int b2 = pix2 / NPIX, n2 = pix2 % NPIX;
        xred[((size_t)b2 * INNER + o) * NPIX + n2] = s;
    }
}

// ---------------------------------------------------------------------------
// Kernel 2a: features. thread = (pixel, dilation i3, out-channel o) (R7).
// Writes FT[j][pix] bf16, j = i3*18 + t*3 + o. Rows 54..63 never written —
// zero-weighted in k_fuse.
// ---------------------------------------------------------------------------
__global__ __launch_bounds__(256) void
k_feat(const float* __restrict__ xred, const float* __restrict__ w_dil,
       const float* __restrict__ b_dil, ushort* __restrict__ FT) {
    int gid = blockIdx.x * 256 + threadIdx.x;      // 9 * 18432 threads exactly
    int io = gid / TOTPIX;                          // wave-uniform (TOTPIX%64==0)
    int pix = gid - io * TOTPIX;
    int i3 = io / 3, o = io - 3 * i3;
    int b = pix / NPIX, n = pix % NPIX;
    int h = n / HW, w = n % HW;
    const float* xr = xred + (size_t)b * INNER * NPIX;
    int d = i3 + 1;

    float co = b_dil[i3 * 3 + o];
    #pragma unroll
    for (int ci = 0; ci < 3; ++ci) {
        const float* xo = xr + ci * NPIX;
        #pragma unroll
        for (int kh = 0; kh < 3; ++kh) {
            int hh = h + (kh - 1) * d;
            #pragma unroll
            for (int kw = 0; kw < 3; ++kw) {
                int ww = w + (kw - 1) * d;
                float v = ((unsigned)hh < HW && (unsigned)ww < HW) ? xo[hh * HW + ww] : 0.f;
                co = fmaf(w_dil[(9 * i3 + 3 * o + ci) * 9 + kh * 3 + kw], v, co);
            }
        }
    }

    const float* xo = xr + o * NPIX;
    float tf0 = xo[h * HW + w];
    float tf1 = xo[h * HW + (HW - 1 - w)];
    float tf2 = xo[(HW - 1 - h) * HW + w];
    float tf3 = xo[w * HW + (HW - 1 - h)];
    float tf4 = xo[(HW - 1 - h) * HW + (HW - 1 - w)];
    float tf5 = xo[(HW - 1 - w) * HW + h];

    size_t base = (size_t)(i3 * 18 + o) * TOTPIX + pix;
    FT[base + (size_t)(0 * 3) * TOTPIX] = f2bf_rne(co * tf0);
    FT[base + (size_t)(1 * 3) * TOTPIX] = f2bf_rne(co * tf1);
    FT[base + (size_t)(2 * 3) * TOTPIX] = f2bf_rne(co * tf2);
    FT[base + (size_t)(3 * 3) * TOTPIX] = f2bf_rne(co * tf3);
    FT[base + (size_t)(4 * 3) * TOTPIX] = f2bf_rne(co * tf4);
    FT[base + (size_t)(5 * 3) * TOTPIX] = f2bf_rne(co * tf5);
}

// ---------------------------------------------------------------------------
// Kernel 2b: fuse conv as MFMA GEMM, 64 px/block (grid 288).
// tokTt is TILED (unpermuted): [b][n>>5][c][n&31]. The in-register-P key
// permutation is applied in k_attn's ldsV staging offsets.
// ---------------------------------------------------------------------------
__global__ __launch_bounds__(256) void
k_fuse(const ushort* __restrict__ FT, const float* __restrict__ w_fuse,
       const float* __restrict__ b_fuse, ushort* __restrict__ tok,
       ushort* __restrict__ tokTt) {
    __shared__ ushort wpad[64 * 72];     // [c][j pad 72]
    __shared__ float  bsh[64];
    __shared__ ushort tile[64 * 72];     // [c][64 px + 8 pad]

    int tid = threadIdx.x;
    for (int i = tid; i < 64 * 64; i += 256) {
        int c = i >> 6, j = i & 63;
        wpad[c * 72 + j] = (j < 54) ? f2bf_rne(w_fuse[c * 54 + j]) : (ushort)0;
    }
    if (tid < 64) bsh[tid] = b_fuse[tid];
    __syncthreads();

    int wv = tid >> 6, lane = tid & 63, quad = lane >> 4, l15 = lane & 15;
    int px0 = blockIdx.x * 64;

    short8 af[4][2];
    #pragma unroll
    for (int m = 0; m < 4; ++m)
        #pragma unroll
        for (int kc = 0; kc < 2; ++kc)
            af[m][kc] = *(const short8*)&wpad[(16 * m + l15) * 72 + quad * 8 + 32 * kc];

    f32x4 acc[4];
    #pragma unroll
    for (int m = 0; m < 4; ++m) acc[m] = (f32x4){0.f, 0.f, 0.f, 0.f};

    int px = px0 + wv * 16 + l15;
    #pragma unroll
    for (int kc = 0; kc < 2; ++kc) {
        short8 bf;
        #pragma unroll
        for (int jj = 0; jj < 8; ++jj)
            bf[jj] = (short)FT[(size_t)(quad * 8 + jj + 32 * kc) * TOTPIX + px];
        #pragma unroll
        for (int m = 0; m < 4; ++m)
            acc[m] = __builtin_amdgcn_mfma_f32_16x16x32_bf16(af[m][kc], bf, acc[m], 0, 0, 0);
    }

    #pragma unroll
    for (int m = 0; m < 4; ++m)
        #pragma unroll
        for (int r = 0; r < 4; ++r) {
            int c = 16 * m + quad * 4 + r;
            tile[c * 72 + wv * 16 + l15] = f2bf_rne(acc[m][r] + bsh[c]);
        }
    __syncthreads();

    int b0 = px0 / NPIX, n0 = px0 % NPIX;
    {   // tok[b][n][c]
        int lp = tid >> 2, part = tid & 3;
        ushort row[16];
        #pragma unroll
        for (int k = 0; k < 16; ++k) row[k] = tile[(part * 16 + k) * 72 + lp];
        ushort* dst = tok + ((size_t)b0 * NPIX + n0 + lp) * NCH + part * 16;
        *(ushort8*)&dst[0] = *(const ushort8*)&row[0];
        *(ushort8*)&dst[8] = *(const ushort8*)&row[8];
    }
    {   // tokTt[b][n>>5][c][n&31] (32-key tiles)
        int c = tid >> 2, seg = tid & 3;
        int n = n0 + seg * 16;
        size_t base = (((size_t)b0 * NT32 + (n >> 5)) * 64 + c) * 32 + (n & 31);
        *(ushort8*)&tokTt[base]     = *(const ushort8*)&tile[c * 72 + seg * 16];
        *(ushort8*)&tokTt[base + 8] = *(const ushort8*)&tile[c * 72 + seg * 16 + 8];
    }
}

// ---------------------------------------------------------------------------
// Kernel 3: MFMA flash attention — R12 k_attn (proven no-spill at (256,5):
// scalar lrun + shfl + atomicAdd, full-line epilogue, XCD swizzle) plus the
// two R13 wins that FIT the 5-wave budget: (a) -FM folded into the S-MFMA
// C-seed (deletes 16 v_sub/body, ~4 regs), (b) P=8 -> grid 1152 <= 1280
// residency slots = single generation + half the pacc traffic.
// R14 lesson: ones-MFMA Lacc + (256,5) = spill (dur 2x, scratch traffic in
// FETCH/WRITE) — denominator stays on the VALU.
// ---------------------------------------------------------------------------
__global__ __launch_bounds__(256, 5) void
k_attn(const ushort* __restrict__ tok, const ushort* __restrict__ tokTt,
       float* __restrict__ L, ushort* __restrict__ pacc, int P, int KP) {
    // staging: ldsK 2x[32*72]=4608 | ldsV 2x[64*40]=5120  (9728 ushorts, 19456 B)
    // epilogue reuse: ot [64][136] = 8704 ushorts
    __shared__ ushort smem[9728];
    ushort* ldsK = smem;            // [cur][key][64ch + 8 pad], cur stride 2304
    ushort* ldsV = smem + 4608;     // [cur][ch][32pos + 8 pad], cur stride 2560

    const int QW = NPIX / 128;          // 72 query chunks per batch
    int bid0 = blockIdx.x;
    int nwg = gridDim.x;                // divisible by 8 for all P candidates
    int bid = (bid0 & 7) * (nwg >> 3) + (bid0 >> 3);   // XCD-chunked swizzle
    int qc = bid % QW; int rest = bid / QW;
    int p = rest % P;  int b = rest / P;
    int tid = threadIdx.x;
    int wv = tid >> 6, lane = tid & 63;
    int quad = lane >> 4, l15 = lane & 15;

    const ushort* tb  = tok + (size_t)b * NPIX * NCH;
    const ushort* tvb = tokTt + (size_t)b * NT32 * (64 * 32);
    int qwave = qc * 128 + wv * 32;

    // staging decomposition (per thread: one 16B chunk of each tile)
    int sk_off = (tid >> 3) * 72 + (tid & 7) * 8;   // [key=tid>>3][ch=(tid&7)*8]
    // V: thread stages ch=tid>>2, keys kk=(tid&3)*8+e. Permuted destination:
    // e=0..3 -> pos base0+e, e=4..7 -> pos base1+(e&3)  (bijective; pairs with
    // the in-register-P key ordering pos = 8*quad + 4*m2 + reg)
    int svj = tid & 3;
    int sv_b0 = (tid >> 2) * 40 + 8 * ((2 * svj) & 3) + 4 * (svj >> 1);
    int sv_b1 = (tid >> 2) * 40 + 8 * ((2 * svj + 1) & 3) + 4 * (svj >> 1);

    // Q fragments: B operand of S^T (lane q=16n+l15, k=quad*8+j+32kc); scale folded.
    short8 qf[2][2];
    const float scale = 0.125f * 1.44269504088896340736f;  // 1/sqrt(C) * log2(e)
    #pragma unroll
    for (int n = 0; n < 2; ++n) {
        const ushort* qr = tb + (size_t)(qwave + 16 * n + l15) * NCH + quad * 8;
        #pragma unroll
        for (int kc = 0; kc < 2; ++kc) {
            ushort8 raw = *(const ushort8*)(qr + 32 * kc);
            short8 f;
            #pragma unroll
            for (int e = 0; e < 8; ++e) f[e] = (short)f2bf_rne(bf2f(raw[e]) * scale);
            qf[n][kc] = f;
        }
    }

    f32x4 O[4][2];                      // O^T acc: D[c=16m+quad*4+reg][q=16n+l15]
    #pragma unroll
    for (int m = 0; m < 4; ++m)
        #pragma unroll
        for (int n = 0; n < 2; ++n) O[m][n] = (f32x4){0.f, 0.f, 0.f, 0.f};
    float lrun[2] = {0.f, 0.f};

    const float FM = 16.0f;             // fixed exp2-domain shift
    const f32x4 FMc = (f32x4){-FM, -FM, -FM, -FM};   // folded into S C-seed

    int k0 = p * KP;
    int nt = KP / 32;

    // strength-reduced staging pointers (advance one 32-key tile per body)
    const ushort* pK = tb + (size_t)k0 * NCH + tid * 8;
    const ushort* pV = tvb + ((size_t)(k0 >> 5)) * 2048 + tid * 8;

    // prologue: stage tile 0
    {
        ushort8 gK = *(const ushort8*)pK;
        ushort8 gV = *(const ushort8*)pV;
        *(ushort8*)&ldsK[sk_off] = gK;
        uint32x4 v4 = *(uint32x4*)&gV;
        *(uint2*)&ldsV[sv_b0] = make_uint2(v4.x, v4.y);
        *(uint2*)&ldsV[sv_b1] = make_uint2(v4.z, v4.w);
    }
    __syncthreads();

    for (int t = 0; t < nt; ++t) {
        int curK = (t & 1) * 2304, curV = (t & 1) * 2560;
        bool pre = (t + 1 < nt);
        pK += 32 * NCH;  pV += 2048;

        // issue next tile's global loads EARLY (latency hides under S phase)
        ushort8 nK, nV;
        if (pre) {
            nK = *(const ushort8*)pK;
            nV = *(const ushort8*)pV;
        }

        // K fragments from LDS (shared by all 4 waves)
        short8 kd[4];
        #pragma unroll
        for (int m2 = 0; m2 < 2; ++m2)
            #pragma unroll
            for (int kc = 0; kc < 2; ++kc)
                kd[2 * m2 + kc] = *(const short8*)&ldsK[curK + (16 * m2 + l15) * 72 +
                                                       quad * 8 + 32 * kc];

        // S^T per-m2 half: 4 MFMA (C seeded with -FM) -> 8 exp2 -> pack
        uint32x4 wac[2];
        #pragma unroll
        for (int m2 = 0; m2 < 2; ++m2) {
            f32x4 Sm[2];
            __builtin_amdgcn_s_setprio(1);
            #pragma unroll
            for (int n = 0; n < 2; ++n) {
                Sm[n] = __builtin_amdgcn_mfma_f32_16x16x32_bf16(kd[2 * m2 + 0],
                                                                qf[n][0], FMc, 0, 0, 0);
                Sm[n] = __builtin_amdgcn_mfma_f32_16x16x32_bf16(kd[2 * m2 + 1],
                                                                qf[n][1], Sm[n], 0, 0, 0);
            }
            __builtin_amdgcn_s_setprio(0);
            #pragma unroll
            for (int n = 0; n < 2; ++n) {
                float e0 = __builtin_amdgcn_exp2f(Sm[n][0]);
                float e1 = __builtin_amdgcn_exp2f(Sm[n][1]);
                float e2 = __builtin_amdgcn_exp2f(Sm[n][2]);
                float e3 = __builtin_amdgcn_exp2f(Sm[n][3]);
                lrun[n] += (e0 + e1) + (e2 + e3);
                if (m2 == 0) {
                    wac[n].x = pack_bf(e0, e1); wac[n].y = pack_bf(e2, e3);
                } else {
                    wac[n].z = pack_bf(e0, e1); wac[n].w = pack_bf(e2, e3);
                }
            }
        }

        // retire staging regs into the OTHER buffer (safe: all reads of that
        // buffer completed before the last barrier)
        if (pre) {
            *(ushort8*)&ldsK[(curK ^ 2304) + sk_off] = nK;
            uint32x4 v4 = *(uint32x4*)&nV;
            *(uint2*)&ldsV[(curV ^ 2560) + sv_b0] = make_uint2(v4.x, v4.y);
            *(uint2*)&ldsV[(curV ^ 2560) + sv_b1] = make_uint2(v4.z, v4.w);
        }

        // V^T fragments (A[ch][pos]) from LDS (permuted key-positions)
        short8 vf[4];
        #pragma unroll
        for (int mc = 0; mc < 4; ++mc)
            vf[mc] = *(const short8*)&ldsV[curV + (16 * mc + l15) * 40 + quad * 8];

        // O^T += V^T·P^T (K=32): P directly from packed registers
        __builtin_amdgcn_s_setprio(1);
        #pragma unroll
        for (int n = 0; n < 2; ++n) {
            short8 bfr = *(short8*)&wac[n];
            #pragma unroll
            for (int mc = 0; mc < 4; ++mc)
                O[mc][n] = __builtin_amdgcn_mfma_f32_16x16x32_bf16(vf[mc], bfr,
                                                                   O[mc][n], 0, 0, 0);
        }
        __builtin_amdgcn_s_setprio(0);

        __syncthreads();               // also guards smem reuse by the epilogue
    }

    #pragma unroll
    for (int n = 0; n < 2; ++n) {       // disjoint key subsets per quad
        lrun[n] += __shfl_xor(lrun[n], 16, 64);
        lrun[n] += __shfl_xor(lrun[n], 32, 64);
    }
    if (quad == 0) {                    // accumulate denominator across p-blocks
        #pragma unroll
        for (int n = 0; n < 2; ++n)
            atomicAdd(&L[(size_t)b * NPIX + qwave + 16 * n + l15], lrun[n]);
    }

    // ---- epilogue: O -> smem tile [64][136], then FULL-LINE pacc writeout ----
    #pragma unroll
    for (int n = 0; n < 2; ++n) {
        int ql = wv * 32 + 16 * n + l15;
        #pragma unroll
        for (int m = 0; m < 4; ++m)
            #pragma unroll
            for (int r = 0; r < 4; ++r)
                smem[(16 * m + quad * 4 + r) * 136 + ql] = f2bf_rne(O[m][n][r]);
    }
    __syncthreads();
    size_t bp = (size_t)b * P + p;
    #pragma unroll
    for (int i = 0; i < 4; ++i) {
        int lin = i * 2048 + tid * 8;
        int c = lin >> 7, q = lin & 127;
        // 16 consecutive lanes cover one 256B row = 4 full 64B lines
        *(ushort8*)(pacc + (bp * NCH + c) * NPIX + qc * 128 + q) =
            *(const ushort8*)&smem[c * 136 + q];
    }
}

// ---------------------------------------------------------------------------
// Kernel 4: fully-coalesced combine with inline normalization. thread =
// (b, c, 8-n segment): o[n] = sum_p pacc[b][p][c][n], out = x + 0.2/L * o.
// ---------------------------------------------------------------------------
__global__ void k_combine(const float* __restrict__ x, const float* __restrict__ L,
                          const ushort* __restrict__ pacc, float* __restrict__ out,
                          int P) {
    int gid = blockIdx.x * blockDim.x + threadIdx.x;   // (b*NCH + c)*1152 + seg
    if (gid >= BB * NCH * (NPIX / 8)) return;
    int seg = gid % (NPIX / 8);
    int bc  = gid / (NPIX / 8);
    int b = bc / NCH;
    int n0 = seg * 8;
    float o[8] = {0.f, 0.f, 0.f, 0.f, 0.f, 0.f, 0.f, 0.f};
    for (int p = 0; p < P; ++p) {
        ushort8 t = *(const ushort8*)(pacc +
            (((size_t)b * P + p) * NCH + (bc % NCH)) * NPIX + n0);
        #pragma unroll
        for (int e = 0; e < 8; ++e) o[e] += bf2f(t[e]);
    }
    const float* lv = L + (size_t)b * NPIX + n0;
    const float* xb = x + (size_t)bc * NPIX + n0;
    float* ob = out + (size_t)bc * NPIX + n0;
    #pragma unroll
    for (int e = 0; e < 8; ++e)
        ob[e] = fmaf(0.2f / lv[e], o[e], xb[e]);
}

// ---------------------------------------------------------------------------
extern "C" void kernel_launch(void* const* d_in, const int* in_sizes, int n_in,
                              void* d_out, int out_size, void* d_ws, size_t ws_size,
                              hipStream_t stream) {
    const float* x      = (const float*)d_in[0];
    const float* w_red  = (const float*)d_in[1];
    const float* b_red  = (const float*)d_in[2];
    const float* w_dil  = (const float*)d_in[3];
    const float* b_dil  = (const float*)d_in[4];
    const float* w_fuse = (const float*)d_in[5];
    const float* b_fuse = (const float*)d_in[6];
    float* out = (float*)d_out;

    // ws: xred f32 | FT bf16 | tok bf16 | tokTt bf16 | L f32 | pacc bf16
    const size_t XRED_N = (size_t)BB * INNER * NPIX;
    const size_t FT_N   = (size_t)64 * TOTPIX;
    const size_t TOK_N  = (size_t)BB * NPIX * NCH;
    const size_t HEAD_B = XRED_N * 4 + (FT_N + 2 * TOK_N) * 2 + TOTPIX * 4;
    int P = 0;
    // P=8: grid 1152 <= 1280 residency slots at 5 blocks/CU -> single
    // generation; pacc traffic half of P=16. KP = NPIX/P multiple of 32 for
    // all cands; grid divisible by 8 (XCD swizzle).
    const int cands[4] = {8, 4, 2, 1};
    for (int ci = 0; ci < 4; ++ci) {
        int cp = cands[ci];
        size_t need = HEAD_B + (size_t)BB * cp * NPIX * NCH * 2;
        if (ws_size >= need) { P = cp; break; }
    }
    if (P == 0) return;

    float*  xred  = (float*)d_ws;
    ushort* FT    = (ushort*)(xred + XRED_N);
    ushort* tok   = FT + FT_N;
    ushort* tokTt = tok + TOK_N;
    float*  L     = (float*)(tokTt + TOK_N);
    ushort* pacc  = (ushort*)(L + TOTPIX);

    k_reduce <<<TOTPIX / 64, 256, 0, stream>>>(x, w_red, b_red, xred, L);
    k_feat   <<<9 * TOTPIX / 256, 256, 0, stream>>>(xred, w_dil, b_dil, FT);
    k_fuse   <<<TOTPIX / 64, 256, 0, stream>>>(FT, w_fuse, b_fuse, tok, tokTt);
    k_attn   <<<BB * P * (NPIX / 128), 256, 0, stream>>>(tok, tokTt, L, pacc,
                                                         P, NPIX / P);
    k_combine<<<(BB * NCH * (NPIX / 8) + 255) / 256, 256, 0, stream>>>(x, L, pacc,
                                                                       out, P);
}

// Round 16
// 135.501 us; speedup vs baseline: 1.3979x; 1.0127x over previous
//
#include <hip/hip_runtime.h>

#define HW    96
#define NPIX  9216        // 96*96
#define NCH   64          // C
#define INNER 3
#define NDIL  3
#define BB    2           // batch
#define TOTPIX (BB * NPIX)   // 18432
#define NT32  (NPIX / 32)    // 288 key tiles per batch

typedef __attribute__((ext_vector_type(8))) short short8;            // 8 bf16
typedef __attribute__((ext_vector_type(8))) unsigned short ushort8;  // 8 bf16 raw
typedef __attribute__((ext_vector_type(4))) float f32x4;
typedef __attribute__((ext_vector_type(4))) unsigned int uint32x4;

__device__ __forceinline__ ushort f2bf_rne(float f) {
    unsigned u = __float_as_uint(f);
    u += 0x7fffu + ((u >> 16) & 1u);
    return (ushort)(u >> 16);
}
__device__ __forceinline__ float bf2f(ushort u) {
    return __uint_as_float((unsigned)u << 16);
}
// pack hi16(a),hi16(b) -> dword {bf16(b)<<16 | bf16(a)} (trunc; ratio-safe for P)
__device__ __forceinline__ unsigned pack_bf(float lo, float hi) {
    return __builtin_amdgcn_perm(__float_as_uint(hi), __float_as_uint(lo), 0x07060302u);
}

// ---------------------------------------------------------------------------
// Kernel 1: x_red = 1x1 conv (64 -> 3 channels). 4-way channel split +
// LDS reduce (R7). Also zeroes L.
// ---------------------------------------------------------------------------
__global__ __launch_bounds__(256) void
k_reduce(const float* __restrict__ x, const float* __restrict__ w_red,
         const float* __restrict__ b_red, float* __restrict__ xred,
         float* __restrict__ L) {
    __shared__ float part[4][3][64];
    int tid = threadIdx.x;
    int gid = blockIdx.x * 256 + tid;
    if (gid < TOTPIX) L[gid] = 0.f;            // fold memset into this kernel
    int cp = tid >> 6, lane = tid & 63;
    int pix = blockIdx.x * 64 + lane;           // block never straddles b
    int b = pix / NPIX, n = pix % NPIX;
    const float* xb = x + (size_t)b * NCH * NPIX + (size_t)(cp * 16) * NPIX + n;
    float a0 = 0.f, a1 = 0.f, a2 = 0.f;
    #pragma unroll
    for (int c = 0; c < 16; ++c) {
        float xv = xb[(size_t)c * NPIX];
        a0 = fmaf(w_red[0 * NCH + cp * 16 + c], xv, a0);
        a1 = fmaf(w_red[1 * NCH + cp * 16 + c], xv, a1);
        a2 = fmaf(w_red[2 * NCH + cp * 16 + c], xv, a2);
    }
    part[cp][0][lane] = a0; part[cp][1][lane] = a1; part[cp][2][lane] = a2;
    __syncthreads();
    if (tid < 192) {
        int o = tid >> 6, lp = tid & 63;
        float s = ((part[0][o][lp] + part[1][o][lp]) +
                   (part[2][o][lp] + part[3][o][lp])) + b_red[o];
        int pix2 = blockIdx.x * 64 + lp;
        int b2 = pix2 / NPIX, n2 = pix2 % NPIX;
        xred[((size_t)b2 * INNER + o) * NPIX + n2] = s;
    }
}

// ---------------------------------------------------------------------------
// Kernel 2 (R16: k_feat FUSED into k_fuse): each 64-px block computes its own
// 54 feature values per pixel into LDS (FTt[j][px], row stride 70: 35 dwords
// -> quad-groups hit disjoint 8-bank sets, conflict-free phase-B reads), then
// runs the MFMA fuse GEMM from LDS. Eliminates the FT global round-trip
// (4.7 MB) and one dispatch. Rows 54..63 explicitly zeroed (zero-weighted in
// wpad; LDS garbage * 0 could be NaN).
// tokTt is TILED (unpermuted): [b][n>>5][c][n&31]; the in-register-P key
// permutation is applied in k_attn's ldsV staging offsets.
// ---------------------------------------------------------------------------
__global__ __launch_bounds__(256) void
k_featfuse(const float* __restrict__ xred, const float* __restrict__ w_dil,
           const float* __restrict__ b_dil, const float* __restrict__ w_fuse,
           const float* __restrict__ b_fuse, ushort* __restrict__ tok,
           ushort* __restrict__ tokTt) {
    __shared__ ushort wpad[64 * 72];     // [c][j pad 72]
    __shared__ float  bsh[64];
    __shared__ ushort FTt[64 * 70];      // [j][64 px + 6 pad], stride 70
    __shared__ ushort tile[64 * 72];     // [c][64 px + 8 pad]

    int tid = threadIdx.x;
    for (int i = tid; i < 64 * 64; i += 256) {
        int c = i >> 6, j = i & 63;
        wpad[c * 72 + j] = (j < 54) ? f2bf_rne(w_fuse[c * 54 + j]) : (ushort)0;
    }
    if (tid < 64) bsh[tid] = b_fuse[tid];

    int px0 = blockIdx.x * 64;

    // ---- phase A: features for this block's 64 pixels -> FTt ----
    if (tid < 192) {                    // waves 0..2: (pixel lp, dilation i3)
        int lp = tid & 63, i3 = tid >> 6;
        int pix = px0 + lp;
        int b = pix / NPIX, n = pix % NPIX;
        int h = n / HW, w = n % HW;
        const float* xr = xred + (size_t)b * INNER * NPIX;
        int d = i3 + 1;

        float co[3] = {b_dil[i3 * 3 + 0], b_dil[i3 * 3 + 1], b_dil[i3 * 3 + 2]};
        #pragma unroll
        for (int ci = 0; ci < 3; ++ci) {
            const float* xo = xr + ci * NPIX;
            #pragma unroll
            for (int kh = 0; kh < 3; ++kh) {
                int hh = h + (kh - 1) * d;
                #pragma unroll
                for (int kw = 0; kw < 3; ++kw) {
                    int ww = w + (kw - 1) * d;
                    float v = ((unsigned)hh < HW && (unsigned)ww < HW)
                                  ? xo[hh * HW + ww] : 0.f;
                    #pragma unroll
                    for (int o = 0; o < 3; ++o)
                        co[o] = fmaf(w_dil[(9 * i3 + 3 * o + ci) * 9 + kh * 3 + kw],
                                     v, co[o]);
                }
            }
        }

        float tf[6][3];
        #pragma unroll
        for (int o = 0; o < 3; ++o) {
            const float* xo = xr + o * NPIX;
            tf[0][o] = xo[h * HW + w];
            tf[1][o] = xo[h * HW + (HW - 1 - w)];
            tf[2][o] = xo[(HW - 1 - h) * HW + w];
            tf[3][o] = xo[w * HW + (HW - 1 - h)];
            tf[4][o] = xo[(HW - 1 - h) * HW + (HW - 1 - w)];
            tf[5][o] = xo[(HW - 1 - w) * HW + h];
        }

        #pragma unroll
        for (int t = 0; t < 6; ++t)
            #pragma unroll
            for (int o = 0; o < 3; ++o)
                FTt[(i3 * 18 + t * 3 + o) * 70 + lp] = f2bf_rne(co[o] * tf[t][o]);
    } else {                            // wave 3: zero rows 54..63
        for (int i = tid - 192; i < 640; i += 64)
            FTt[(54 + (i >> 6)) * 70 + (i & 63)] = (ushort)0;
    }
    __syncthreads();

    // ---- phase B: fuse conv as MFMA GEMM (B-fragments from FTt) ----
    int wv = tid >> 6, lane = tid & 63, quad = lane >> 4, l15 = lane & 15;

    short8 af[4][2];
    #pragma unroll
    for (int m = 0; m < 4; ++m)
        #pragma unroll
        for (int kc = 0; kc < 2; ++kc)
            af[m][kc] = *(const short8*)&wpad[(16 * m + l15) * 72 + quad * 8 + 32 * kc];

    f32x4 acc[4];
    #pragma unroll
    for (int m = 0; m < 4; ++m) acc[m] = (f32x4){0.f, 0.f, 0.f, 0.f};

    int pxl = wv * 16 + l15;
    #pragma unroll
    for (int kc = 0; kc < 2; ++kc) {
        short8 bf;
        #pragma unroll
        for (int jj = 0; jj < 8; ++jj)
            bf[jj] = (short)FTt[(quad * 8 + jj + 32 * kc) * 70 + pxl];
        #pragma unroll
        for (int m = 0; m < 4; ++m)
            acc[m] = __builtin_amdgcn_mfma_f32_16x16x32_bf16(af[m][kc], bf, acc[m], 0, 0, 0);
    }

    #pragma unroll
    for (int m = 0; m < 4; ++m)
        #pragma unroll
        for (int r = 0; r < 4; ++r) {
            int c = 16 * m + quad * 4 + r;
            tile[c * 72 + wv * 16 + l15] = f2bf_rne(acc[m][r] + bsh[c]);
        }
    __syncthreads();

    int b0 = px0 / NPIX, n0 = px0 % NPIX;
    {   // tok[b][n][c]
        int lp = tid >> 2, part = tid & 3;
        ushort row[16];
        #pragma unroll
        for (int k = 0; k < 16; ++k) row[k] = tile[(part * 16 + k) * 72 + lp];
        ushort* dst = tok + ((size_t)b0 * NPIX + n0 + lp) * NCH + part * 16;
        *(ushort8*)&dst[0] = *(const ushort8*)&row[0];
        *(ushort8*)&dst[8] = *(const ushort8*)&row[8];
    }
    {   // tokTt[b][n>>5][c][n&31] (32-key tiles)
        int c = tid >> 2, seg = tid & 3;
        int n = n0 + seg * 16;
        size_t base = (((size_t)b0 * NT32 + (n >> 5)) * 64 + c) * 32 + (n & 31);
        *(ushort8*)&tokTt[base]     = *(const ushort8*)&tile[c * 72 + seg * 16];
        *(ushort8*)&tokTt[base + 8] = *(const ushort8*)&tile[c * 72 + seg * 16 + 8];
    }
}

// ---------------------------------------------------------------------------
// Kernel 3: MFMA flash attention — R15 kernel verbatim (best stable: 57 µs,
// no spill at (256,5); scalar lrun + shfl + atomicAdd, -FM in MFMA C-seed,
// full-line epilogue, XCD swizzle, P=8 single residency generation).
// ---------------------------------------------------------------------------
__global__ __launch_bounds__(256, 5) void
k_attn(const ushort* __restrict__ tok, const ushort* __restrict__ tokTt,
       float* __restrict__ L, ushort* __restrict__ pacc, int P, int KP) {
    // staging: ldsK 2x[32*72]=4608 | ldsV 2x[64*40]=5120  (9728 ushorts, 19456 B)
    // epilogue reuse: ot [64][136] = 8704 ushorts
    __shared__ ushort smem[9728];
    ushort* ldsK = smem;            // [cur][key][64ch + 8 pad], cur stride 2304
    ushort* ldsV = smem + 4608;     // [cur][ch][32pos + 8 pad], cur stride 2560

    const int QW = NPIX / 128;          // 72 query chunks per batch
    int bid0 = blockIdx.x;
    int nwg = gridDim.x;                // divisible by 8 for all P candidates
    int bid = (bid0 & 7) * (nwg >> 3) + (bid0 >> 3);   // XCD-chunked swizzle
    int qc = bid % QW; int rest = bid / QW;
    int p = rest % P;  int b = rest / P;
    int tid = threadIdx.x;
    int wv = tid >> 6, lane = tid & 63;
    int quad = lane >> 4, l15 = lane & 15;

    const ushort* tb  = tok + (size_t)b * NPIX * NCH;
    const ushort* tvb = tokTt + (size_t)b * NT32 * (64 * 32);
    int qwave = qc * 128 + wv * 32;

    // staging decomposition (per thread: one 16B chunk of each tile)
    int sk_off = (tid >> 3) * 72 + (tid & 7) * 8;   // [key=tid>>3][ch=(tid&7)*8]
    // V: thread stages ch=tid>>2, keys kk=(tid&3)*8+e. Permuted destination:
    // e=0..3 -> pos base0+e, e=4..7 -> pos base1+(e&3)  (bijective; pairs with
    // the in-register-P key ordering pos = 8*quad + 4*m2 + reg)
    int svj = tid & 3;
    int sv_b0 = (tid >> 2) * 40 + 8 * ((2 * svj) & 3) + 4 * (svj >> 1);
    int sv_b1 = (tid >> 2) * 40 + 8 * ((2 * svj + 1) & 3) + 4 * (svj >> 1);

    // Q fragments: B operand of S^T (lane q=16n+l15, k=quad*8+j+32kc); scale folded.
    short8 qf[2][2];
    const float scale = 0.125f * 1.44269504088896340736f;  // 1/sqrt(C) * log2(e)
    #pragma unroll
    for (int n = 0; n < 2; ++n) {
        const ushort* qr = tb + (size_t)(qwave + 16 * n + l15) * NCH + quad * 8;
        #pragma unroll
        for (int kc = 0; kc < 2; ++kc) {
            ushort8 raw = *(const ushort8*)(qr + 32 * kc);
            short8 f;
            #pragma unroll
            for (int e = 0; e < 8; ++e) f[e] = (short)f2bf_rne(bf2f(raw[e]) * scale);
            qf[n][kc] = f;
        }
    }

    f32x4 O[4][2];                      // O^T acc: D[c=16m+quad*4+reg][q=16n+l15]
    #pragma unroll
    for (int m = 0; m < 4; ++m)
        #pragma unroll
        for (int n = 0; n < 2; ++n) O[m][n] = (f32x4){0.f, 0.f, 0.f, 0.f};
    float lrun[2] = {0.f, 0.f};

    const float FM = 16.0f;             // fixed exp2-domain shift
    const f32x4 FMc = (f32x4){-FM, -FM, -FM, -FM};   // folded into S C-seed

    int k0 = p * KP;
    int nt = KP / 32;

    // strength-reduced staging pointers (advance one 32-key tile per body)
    const ushort* pK = tb + (size_t)k0 * NCH + tid * 8;
    const ushort* pV = tvb + ((size_t)(k0 >> 5)) * 2048 + tid * 8;

    // prologue: stage tile 0
    {
        ushort8 gK = *(const ushort8*)pK;
        ushort8 gV = *(const ushort8*)pV;
        *(ushort8*)&ldsK[sk_off] = gK;
        uint32x4 v4 = *(uint32x4*)&gV;
        *(uint2*)&ldsV[sv_b0] = make_uint2(v4.x, v4.y);
        *(uint2*)&ldsV[sv_b1] = make_uint2(v4.z, v4.w);
    }
    __syncthreads();

    for (int t = 0; t < nt; ++t) {
        int curK = (t & 1) * 2304, curV = (t & 1) * 2560;
        bool pre = (t + 1 < nt);
        pK += 32 * NCH;  pV += 2048;

        // issue next tile's global loads EARLY (latency hides under S phase)
        ushort8 nK, nV;
        if (pre) {
            nK = *(const ushort8*)pK;
            nV = *(const ushort8*)pV;
        }

        // K fragments from LDS (shared by all 4 waves)
        short8 kd[4];
        #pragma unroll
        for (int m2 = 0; m2 < 2; ++m2)
            #pragma unroll
            for (int kc = 0; kc < 2; ++kc)
                kd[2 * m2 + kc] = *(const short8*)&ldsK[curK + (16 * m2 + l15) * 72 +
                                                       quad * 8 + 32 * kc];

        // S^T per-m2 half: 4 MFMA (C seeded with -FM) -> 8 exp2 -> pack
        uint32x4 wac[2];
        #pragma unroll
        for (int m2 = 0; m2 < 2; ++m2) {
            f32x4 Sm[2];
            __builtin_amdgcn_s_setprio(1);
            #pragma unroll
            for (int n = 0; n < 2; ++n) {
                Sm[n] = __builtin_amdgcn_mfma_f32_16x16x32_bf16(kd[2 * m2 + 0],
                                                                qf[n][0], FMc, 0, 0, 0);
                Sm[n] = __builtin_amdgcn_mfma_f32_16x16x32_bf16(kd[2 * m2 + 1],
                                                                qf[n][1], Sm[n], 0, 0, 0);
            }
            __builtin_amdgcn_s_setprio(0);
            #pragma unroll
            for (int n = 0; n < 2; ++n) {
                float e0 = __builtin_amdgcn_exp2f(Sm[n][0]);
                float e1 = __builtin_amdgcn_exp2f(Sm[n][1]);
                float e2 = __builtin_amdgcn_exp2f(Sm[n][2]);
                float e3 = __builtin_amdgcn_exp2f(Sm[n][3]);
                lrun[n] += (e0 + e1) + (e2 + e3);
                if (m2 == 0) {
                    wac[n].x = pack_bf(e0, e1); wac[n].y = pack_bf(e2, e3);
                } else {
                    wac[n].z = pack_bf(e0, e1); wac[n].w = pack_bf(e2, e3);
                }
            }
        }

        // retire staging regs into the OTHER buffer (safe: all reads of that
        // buffer completed before the last barrier)
        if (pre) {
            *(ushort8*)&ldsK[(curK ^ 2304) + sk_off] = nK;
            uint32x4 v4 = *(uint32x4*)&nV;
            *(uint2*)&ldsV[(curV ^ 2560) + sv_b0] = make_uint2(v4.x, v4.y);
            *(uint2*)&ldsV[(curV ^ 2560) + sv_b1] = make_uint2(v4.z, v4.w);
        }

        // V^T fragments (A[ch][pos]) from LDS (permuted key-positions)
        short8 vf[4];
        #pragma unroll
        for (int mc = 0; mc < 4; ++mc)
            vf[mc] = *(const short8*)&ldsV[curV + (16 * mc + l15) * 40 + quad * 8];

        // O^T += V^T·P^T (K=32): P directly from packed registers
        __builtin_amdgcn_s_setprio(1);
        #pragma unroll
        for (int n = 0; n < 2; ++n) {
            short8 bfr = *(short8*)&wac[n];
            #pragma unroll
            for (int mc = 0; mc < 4; ++mc)
                O[mc][n] = __builtin_amdgcn_mfma_f32_16x16x32_bf16(vf[mc], bfr,
                                                                   O[mc][n], 0, 0, 0);
        }
        __builtin_amdgcn_s_setprio(0);

        __syncthreads();               // also guards smem reuse by the epilogue
    }

    #pragma unroll
    for (int n = 0; n < 2; ++n) {       // disjoint key subsets per quad
        lrun[n] += __shfl_xor(lrun[n], 16, 64);
        lrun[n] += __shfl_xor(lrun[n], 32, 64);
    }
    if (quad == 0) {                    // accumulate denominator across p-blocks
        #pragma unroll
        for (int n = 0; n < 2; ++n)
            atomicAdd(&L[(size_t)b * NPIX + qwave + 16 * n + l15], lrun[n]);
    }

    // ---- epilogue: O -> smem tile [64][136], then FULL-LINE pacc writeout ----
    #pragma unroll
    for (int n = 0; n < 2; ++n) {
        int ql = wv * 32 + 16 * n + l15;
        #pragma unroll
        for (int m = 0; m < 4; ++m)
            #pragma unroll
            for (int r = 0; r < 4; ++r)
                smem[(16 * m + quad * 4 + r) * 136 + ql] = f2bf_rne(O[m][n][r]);
    }
    __syncthreads();
    size_t bp = (size_t)b * P + p;
    #pragma unroll
    for (int i = 0; i < 4; ++i) {
        int lin = i * 2048 + tid * 8;
        int c = lin >> 7, q = lin & 127;
        // 16 consecutive lanes cover one 256B row = 4 full 64B lines
        *(ushort8*)(pacc + (bp * NCH + c) * NPIX + qc * 128 + q) =
            *(const ushort8*)&smem[c * 136 + q];
    }
}

// ---------------------------------------------------------------------------
// Kernel 4: fully-coalesced combine with inline normalization. thread =
// (b, c, 8-n segment): o[n] = sum_p pacc[b][p][c][n], out = x + 0.2/L * o.
// ---------------------------------------------------------------------------
__global__ void k_combine(const float* __restrict__ x, const float* __restrict__ L,
                          const ushort* __restrict__ pacc, float* __restrict__ out,
                          int P) {
    int gid = blockIdx.x * blockDim.x + threadIdx.x;   // (b*NCH + c)*1152 + seg
    if (gid >= BB * NCH * (NPIX / 8)) return;
    int seg = gid % (NPIX / 8);
    int bc  = gid / (NPIX / 8);
    int b = bc / NCH;
    int n0 = seg * 8;
    float o[8] = {0.f, 0.f, 0.f, 0.f, 0.f, 0.f, 0.f, 0.f};
    for (int p = 0; p < P; ++p) {
        ushort8 t = *(const ushort8*)(pacc +
            (((size_t)b * P + p) * NCH + (bc % NCH)) * NPIX + n0);
        #pragma unroll
        for (int e = 0; e < 8; ++e) o[e] += bf2f(t[e]);
    }
    const float* lv = L + (size_t)b * NPIX + n0;
    const float* xb = x + (size_t)bc * NPIX + n0;
    float* ob = out + (size_t)bc * NPIX + n0;
    #pragma unroll
    for (int e = 0; e < 8; ++e)
        ob[e] = fmaf(0.2f / lv[e], o[e], xb[e]);
}

// ---------------------------------------------------------------------------
extern "C" void kernel_launch(void* const* d_in, const int* in_sizes, int n_in,
                              void* d_out, int out_size, void* d_ws, size_t ws_size,
                              hipStream_t stream) {
    const float* x      = (const float*)d_in[0];
    const float* w_red  = (const float*)d_in[1];
    const float* b_red  = (const float*)d_in[2];
    const float* w_dil  = (const float*)d_in[3];
    const float* b_dil  = (const float*)d_in[4];
    const float* w_fuse = (const float*)d_in[5];
    const float* b_fuse = (const float*)d_in[6];
    float* out = (float*)d_out;

    // ws: xred f32 | tok bf16 | tokTt bf16 | L f32 | pacc bf16   (FT removed)
    const size_t XRED_N = (size_t)BB * INNER * NPIX;
    const size_t TOK_N  = (size_t)BB * NPIX * NCH;
    const size_t HEAD_B = XRED_N * 4 + 2 * TOK_N * 2 + TOTPIX * 4;
    int P = 0;
    // P=8: grid 1152 <= 1280 residency slots at 5 blocks/CU -> single
    // generation; KP = NPIX/P multiple of 32 for all cands; grid divisible
    // by 8 (XCD swizzle).
    const int cands[4] = {8, 4, 2, 1};
    for (int ci = 0; ci < 4; ++ci) {
        int cp = cands[ci];
        size_t need = HEAD_B + (size_t)BB * cp * NPIX * NCH * 2;
        if (ws_size >= need) { P = cp; break; }
    }
    if (P == 0) return;

    float*  xred  = (float*)d_ws;
    ushort* tok   = (ushort*)(xred + XRED_N);
    ushort* tokTt = tok + TOK_N;
    float*  L     = (float*)(tokTt + TOK_N);
    ushort* pacc  = (ushort*)(L + TOTPIX);

    k_reduce  <<<TOTPIX / 64, 256, 0, stream>>>(x, w_red, b_red, xred, L);
    k_featfuse<<<TOTPIX / 64, 256, 0, stream>>>(xred, w_dil, b_dil, w_fuse,
                                                b_fuse, tok, tokTt);
    k_attn    <<<BB * P * (NPIX / 128), 256, 0, stream>>>(tok, tokTt, L, pacc,
                                                          P, NPIX / P);
    k_combine <<<(BB * NCH * (NPIX / 8) + 255) / 256, 256, 0, stream>>>(x, L, pacc,
                                                                        out, P);
}